// Round 8
// baseline (280.127 us; speedup 1.0000x reference)
//
#include <hip/hip_runtime.h>
#include <stdint.h>

// B=8, C=128, N=4096 (64x64), GROUPS=8 (16 ch/group)
// Split-KV flash attention, 32x32x16 MFMA quadrants, max-free base-2 softmax.
// R8: K fragments stream straight from global (L1/L2) — no K_lds, 2 barriers/iter;
//     GroupNorm stats parallelized to 1024 blocks via atomicAdd partial sums.

typedef __attribute__((ext_vector_type(8))) short short8;
typedef __attribute__((ext_vector_type(4))) float f32x4;
typedef __attribute__((ext_vector_type(16))) float f32x16;

#define MFMA_BF16(a, b, c) __builtin_amdgcn_mfma_f32_16x16x32_bf16((a), (b), (c), 0, 0, 0)
#define MFMA32(a, b, c) __builtin_amdgcn_mfma_f32_32x32x16_bf16((a), (b), (c), 0, 0, 0)
#define EXP2(x) __builtin_amdgcn_exp2f(x)

// (1/sqrt(128)) * log2(e) — folded into Q at k_qkv store time (softmax runs in base 2)
#define QSCALE 0.12751743f

__device__ __forceinline__ unsigned short f2bf(float f) {
    unsigned int u = __builtin_bit_cast(unsigned int, f);
    u += 0x7FFFu + ((u >> 16) & 1u);   // RNE (finite values only)
    return (unsigned short)(u >> 16);
}
__device__ __forceinline__ float bf2f(unsigned int lo16) {
    return __builtin_bit_cast(float, lo16 << 16);
}
__device__ __forceinline__ short8 ldg8(const unsigned short* p) {
    return __builtin_bit_cast(short8, *(const uint4*)p);
}

// ---------------- Kernel 1: GroupNorm partial sums (atomic) + weight bf16 conv ------
// blocks 0..1023: 16 blocks per (b,g) group, each reduces 4096 floats -> 2 atomicAdds.
// blocks 1024..1087: fp32 -> bf16 weight conversion.
__global__ __launch_bounds__(256) void k_pre(const float* __restrict__ x,
                                             float* __restrict__ sums,
                                             const float* __restrict__ qkv_w,
                                             const float* __restrict__ proj_w,
                                             unsigned short* __restrict__ wq,
                                             unsigned short* __restrict__ wp) {
    if (blockIdx.x >= 1024) {            // weight conversion: 64 blocks x 1024 elems
        int i = ((blockIdx.x - 1024) * 256 + threadIdx.x) * 4;
        const float* src; unsigned short* dst; int off;
        if (i < 49152) { src = qkv_w; dst = wq; off = i; }
        else           { src = proj_w; dst = wp; off = i - 49152; }
        float4 v = *(const float4*)(src + off);
        uint2 pk;
        pk.x = (unsigned int)f2bf(v.x) | ((unsigned int)f2bf(v.y) << 16);
        pk.y = (unsigned int)f2bf(v.z) | ((unsigned int)f2bf(v.w) << 16);
        *(uint2*)(dst + off) = pk;
        return;
    }
    int g     = blockIdx.x >> 4;         // 0..63 (b*8+gr); group slab contiguous
    int slice = blockIdx.x & 15;
    const float* p = x + (size_t)g * 65536 + slice * 4096;
    float s = 0.f, sq = 0.f;
#pragma unroll
    for (int i = 0; i < 4; ++i) {
        float4 v = *(const float4*)(p + threadIdx.x * 4 + i * 1024);
        s  += v.x + v.y + v.z + v.w;
        sq += v.x*v.x + v.y*v.y + v.z*v.z + v.w*v.w;
    }
#pragma unroll
    for (int m = 1; m < 64; m <<= 1) { s += __shfl_xor(s, m, 64); sq += __shfl_xor(sq, m, 64); }
    __shared__ float ss[4], ssq[4];
    int w = threadIdx.x >> 6;
    if ((threadIdx.x & 63) == 0) { ss[w] = s; ssq[w] = sq; }
    __syncthreads();
    if (threadIdx.x == 0) {
        atomicAdd(&sums[g * 2],     ss[0] + ss[1] + ss[2] + ss[3]);
        atomicAdd(&sums[g * 2 + 1], ssq[0] + ssq[1] + ssq[2] + ssq[3]);
    }
}

// ---------------- Kernel 2: fused GroupNorm-apply + QKV GEMM ----------------
// Q (pre-scaled by QSCALE), K as bf16 [b][n][c]; V as bf16 [b][c][n].
__global__ __launch_bounds__(256) void k_qkv(const float* __restrict__ x,
                                             const float* __restrict__ sums,
                                             const float* __restrict__ gn_w,
                                             const float* __restrict__ gn_b,
                                             const unsigned short* __restrict__ wq,
                                             const float* __restrict__ qkv_b,
                                             unsigned short* __restrict__ q_ws,
                                             unsigned short* __restrict__ k_ws,
                                             unsigned short* __restrict__ v_ws) {
    __shared__ unsigned short h_lds[64][136];   // [n][c], +8 pad
    __shared__ unsigned short v_stage[128][72]; // [c][n_local], +8 pad
    const int tid  = threadIdx.x;
    const int b    = blockIdx.x >> 6;
    const int n0   = (blockIdx.x & 63) << 6;
    const int lane = tid & 63, wave = tid >> 6;
    const int l15  = lane & 15, q4 = lane >> 4;

    // normalize x tile -> bf16 -> h_lds[n][c]
    {
        int cb = tid >> 4;            // 0..15
        int nn = (tid & 15) << 2;     // 0..60
#pragma unroll
        for (int k = 0; k < 8; ++k) {
            int c = cb + (k << 4);
            float4 v = *(const float4*)(x + ((size_t)(b * 128 + c) << 12) + n0 + nn);
            int g = c >> 4;
            float ts = sums[(b * 8 + g) * 2];
            float tq = sums[(b * 8 + g) * 2 + 1];
            float mean = ts * (1.f / 65536.f);
            float var  = tq * (1.f / 65536.f) - mean * mean;
            float rstd = rsqrtf(var + 1e-5f);
            float ga = gn_w[c] * rstd;
            float be = gn_b[c] - mean * ga;
            h_lds[nn + 0][c] = f2bf(v.x * ga + be);
            h_lds[nn + 1][c] = f2bf(v.y * ga + be);
            h_lds[nn + 2][c] = f2bf(v.z * ga + be);
            h_lds[nn + 3][c] = f2bf(v.w * ga + be);
        }
    }
    __syncthreads();

    short8 bfrag[4][4];               // B[k=c][n], n=l15
#pragma unroll
    for (int nt = 0; nt < 4; ++nt)
#pragma unroll
        for (int ks = 0; ks < 4; ++ks)
            bfrag[nt][ks] = *(const short8*)&h_lds[nt * 16 + l15][ks * 32 + q4 * 8];

#pragma unroll
    for (int ot = 0; ot < 6; ++ot) {
        int o0 = wave * 96 + ot * 16;                 // 16-row tile is purely Q, K, or V
        short8 af[4];                                 // A[m=o][k=c], m=l15 (bf16 weights)
#pragma unroll
        for (int ks = 0; ks < 4; ++ks)
            af[ks] = ldg8(wq + (size_t)(o0 + l15) * 128 + ks * 32 + q4 * 8);
        float bias[4];
#pragma unroll
        for (int r = 0; r < 4; ++r) bias[r] = qkv_b[o0 + q4 * 4 + r];
        float qs = (o0 < 128) ? QSCALE : 1.0f;

#pragma unroll
        for (int nt = 0; nt < 4; ++nt) {
            f32x4 acc = {0.f, 0.f, 0.f, 0.f};
#pragma unroll
            for (int ks = 0; ks < 4; ++ks)
                acc = MFMA_BF16(af[ks], bfrag[nt][ks], acc);
            // D[row = o0+q4*4+r][col = n0+nt*16+l15]
            int n = n0 + nt * 16 + l15;
            if (o0 < 256) {           // Q or K: [n][c] layout, 4 consecutive c -> 8B store
                unsigned short* dst = (o0 < 128) ? q_ws : k_ws;
                int oo = (o0 < 128) ? o0 : (o0 - 128);
                unsigned int lo = (unsigned int)f2bf((acc[0] + bias[0]) * qs) |
                                  ((unsigned int)f2bf((acc[1] + bias[1]) * qs) << 16);
                unsigned int hi = (unsigned int)f2bf((acc[2] + bias[2]) * qs) |
                                  ((unsigned int)f2bf((acc[3] + bias[3]) * qs) << 16);
                uint2 pk; pk.x = lo; pk.y = hi;
                *(uint2*)&dst[((size_t)(b * 4096 + n) << 7) + oo + q4 * 4] = pk;
            } else {                  // V: stage to LDS [c][n_local]
#pragma unroll
                for (int r = 0; r < 4; ++r) {
                    int c = o0 - 256 + q4 * 4 + r;
                    v_stage[c][nt * 16 + l15] = f2bf(acc[r] + bias[r]);
                }
            }
        }
    }
    __syncthreads();
    // packed V store: thread t copies half-row (32 shorts) of v_stage row c=t>>1
    {
        int c = tid >> 1, hh = tid & 1;
        uint4* gdst = (uint4*)(v_ws + ((size_t)(b * 128 + c) << 12) + n0 + hh * 32);
        const unsigned short* lsrc = &v_stage[c][hh * 32];
#pragma unroll
        for (int k = 0; k < 4; ++k) gdst[k] = *(const uint4*)(lsrc + k * 8);
    }
}

// ---------------- Kernel 3: flash attention partial (split-KV, 32x32 quadrants) ----
// block = 256 threads / 4 waves = (b, i-tile, chunk); chunk covers 1024 j.
// QK: wave (ih,jh) computes S quadrant [32i x 32j], K fragments STRAIGHT FROM GLOBAL
// (K[n][c] row-major == A-frag layout; both ih-waves hit the same L1 lines).
// PV: wave computes O[32i x 64c]; V and P via LDS. 2 barriers/iter, nothing
// register-held across MFMA regions (the r5/r6 spill lesson).
__global__ __launch_bounds__(256, 4) void k_attn_part(const unsigned short* __restrict__ q_ws,
                                                      const unsigned short* __restrict__ k_ws,
                                                      const unsigned short* __restrict__ v_ws,
                                                      unsigned short* __restrict__ o_part,
                                                      float* __restrict__ ml) {
    __shared__ unsigned short V_lds[128][72];   // [c][j], +8 pad  (18432 B)
    __shared__ unsigned short P_lds[64][72];    // [i][j], +8 pad  ( 9216 B)  ~27 KB total

    const int tid   = threadIdx.x;
    const int chunk = blockIdx.x & 3;
    const int tile  = (blockIdx.x >> 2) & 63;
    const int b     = blockIdx.x >> 8;
    const int i0    = tile << 6;
    const int lane  = tid & 63, wave = tid >> 6;
    const int ih    = wave >> 1, jh = wave & 1;   // jh doubles as c-half in PV
    const int l31   = lane & 31, h = lane >> 5;

    const short8 ones = {(short)0x3F80, (short)0x3F80, (short)0x3F80, (short)0x3F80,
                         (short)0x3F80, (short)0x3F80, (short)0x3F80, (short)0x3F80};

    // Q A-frags: A[m = i = l31][k = ks*16 + h*8 + e]  (pre-scaled by QSCALE)
    short8 qf[8];
    {
        const unsigned short* qp =
            q_ws + ((size_t)(b * 4096 + i0 + ih * 32 + l31) << 7) + h * 8;
#pragma unroll
        for (int ks = 0; ks < 8; ++ks) qf[ks] = ldg8(qp + ks * 16);
    }

    f32x16 acc[2];                           // O[i][c = jh*64 + ct*32 + l31]
    f32x16 lacc;                             // row sums (every col identical)
#pragma unroll
    for (int e = 0; e < 16; ++e) { lacc[e] = 0.f; acc[0][e] = 0.f; acc[1][e] = 0.f; }

    // per-lane global K fragment base: row jh*32+l31, col h*8 of K[b][n][c]
    const unsigned short* kfp = k_ws + ((size_t)b << 19) +
                                ((size_t)(jh * 32 + l31) << 7) + h * 8;
    const unsigned short* vsrc = v_ws + ((size_t)b << 19) +
                                 ((size_t)(tid >> 1) << 12) + (tid & 1) * 32;

    for (int it = 0; it < 16; ++it) {
        int j0 = (chunk << 10) + (it << 6);
        __syncthreads();                      // prev iter's V/P reads done
        {   // stage V tile [128 c][72-pitch j] — load+store immediately, no reg hold
            const unsigned short* vp = vsrc + j0;
            uint4* vd = (uint4*)&V_lds[tid >> 1][(tid & 1) * 32];
#pragma unroll
            for (int k = 0; k < 4; ++k) vd[k] = *(const uint4*)(vp + k * 8);
        }

        // S quadrant = Q K^T, K straight from global (L1/L2):
        // D row = i = (r&3)+8(r>>2)+4h (in ih half), col = j = l31 (in jh half)
        f32x16 s;
#pragma unroll
        for (int e = 0; e < 16; ++e) s[e] = 0.f;
        const unsigned short* kp = kfp + ((size_t)j0 << 7);
#pragma unroll
        for (int ks = 0; ks < 8; ++ks)
            s = MFMA32(qf[ks], ldg8(kp + ks * 16), s);

        // max-free softmax: p = exp2(min(s,30)) -> shared P_lds quadrant
#pragma unroll
        for (int r = 0; r < 16; ++r) {
            int row = ih * 32 + (r & 3) + ((r >> 2) << 3) + (h << 2);
            P_lds[row][jh * 32 + l31] = f2bf(EXP2(fminf(s[r], 30.f)));
        }
        __syncthreads();                      // V + P visible

        // O += P V^T ; l += P.1   (A = P[i][j], B = V^T[j][c])
#pragma unroll
        for (int ks = 0; ks < 4; ++ks) {
            short8 pf = *(const short8*)&P_lds[ih * 32 + l31][ks * 16 + h * 8];
            lacc = MFMA32(pf, ones, lacc);
#pragma unroll
            for (int ct = 0; ct < 2; ++ct) {
                short8 vf = *(const short8*)&V_lds[jh * 64 + ct * 32 + l31][ks * 16 + h * 8];
                acc[ct] = MFMA32(pf, vf, acc[ct]);
            }
        }
    }

    // epilogue: normalize rows, store bf16 partial [n][c] + m' = log2(l)
    size_t pbase = (size_t)((b * 64 + tile) * 4 + chunk) * 8192;
    float rl[16];
#pragma unroll
    for (int r = 0; r < 16; ++r) rl[r] = 1.0f / lacc[r];
#pragma unroll
    for (int ct = 0; ct < 2; ++ct)
#pragma unroll
        for (int r = 0; r < 16; ++r) {
            int row = ih * 32 + (r & 3) + ((r >> 2) << 3) + (h << 2);
            o_part[pbase + (size_t)row * 128 + jh * 64 + ct * 32 + l31] =
                f2bf(acc[ct][r] * rl[r]);
        }
    if (l31 == 0 && jh == 0) {
        int mb = ((b * 64 + tile) * 4 + chunk) * 64;
#pragma unroll
        for (int r = 0; r < 16; ++r)
            ml[mb + ih * 32 + (r & 3) + ((r >> 2) << 3) + (h << 2)] = __log2f(lacc[r]);
    }
}

// ---------------- Kernel 4: merge partials + proj GEMM + bias + residual ----------
__global__ __launch_bounds__(256) void k_merge_proj(const unsigned short* __restrict__ o_part,
                                                    const float* __restrict__ ml,
                                                    const float* __restrict__ x,
                                                    const unsigned short* __restrict__ wp,
                                                    const float* __restrict__ proj_b,
                                                    float* __restrict__ out) {
    __shared__ unsigned short O_lds[64][136];
    __shared__ float wgt[64][4];
    const int tid  = threadIdx.x;
    const int b    = blockIdx.x >> 6;
    const int tile = blockIdx.x & 63;
    const int i0   = tile << 6;
    const int lane = tid & 63, wave = tid >> 6;
    const int l15  = lane & 15, q4 = lane >> 4;
    const int tb   = (b * 64 + tile) * 4;

    if (tid < 64) {
        float m0 = ml[(tb + 0) * 64 + tid], m1 = ml[(tb + 1) * 64 + tid];
        float m2 = ml[(tb + 2) * 64 + tid], m3 = ml[(tb + 3) * 64 + tid];
        float M = fmaxf(fmaxf(m0, m1), fmaxf(m2, m3));
        float w0 = EXP2(m0 - M), w1 = EXP2(m1 - M), w2 = EXP2(m2 - M), w3 = EXP2(m3 - M);
        float rW = 1.0f / (w0 + w1 + w2 + w3);
        wgt[tid][0] = w0 * rW; wgt[tid][1] = w1 * rW;
        wgt[tid][2] = w2 * rW; wgt[tid][3] = w3 * rW;
    }
    __syncthreads();

    {   // weighted merge: thread t -> row n=t>>2, 32-c quarter q=t&3
        int n = tid >> 2, q = tid & 3;
        float w[4];
#pragma unroll
        for (int ch = 0; ch < 4; ++ch) w[ch] = wgt[n][ch];
#pragma unroll
        for (int g = 0; g < 4; ++g) {             // 8 c per group
            float acc[8];
#pragma unroll
            for (int e = 0; e < 8; ++e) acc[e] = 0.f;
#pragma unroll
            for (int ch = 0; ch < 4; ++ch) {
                const unsigned short* p =
                    o_part + (size_t)(tb + ch) * 8192 + (size_t)n * 128 + q * 32 + g * 8;
                uint4 v = *(const uint4*)p;
                float wc = w[ch];
                acc[0] += wc * bf2f(v.x & 0xFFFF); acc[1] += wc * bf2f(v.x >> 16);
                acc[2] += wc * bf2f(v.y & 0xFFFF); acc[3] += wc * bf2f(v.y >> 16);
                acc[4] += wc * bf2f(v.z & 0xFFFF); acc[5] += wc * bf2f(v.z >> 16);
                acc[6] += wc * bf2f(v.w & 0xFFFF); acc[7] += wc * bf2f(v.w >> 16);
            }
            uint4 pk;
            pk.x = (unsigned int)f2bf(acc[0]) | ((unsigned int)f2bf(acc[1]) << 16);
            pk.y = (unsigned int)f2bf(acc[2]) | ((unsigned int)f2bf(acc[3]) << 16);
            pk.z = (unsigned int)f2bf(acc[4]) | ((unsigned int)f2bf(acc[5]) << 16);
            pk.w = (unsigned int)f2bf(acc[6]) | ((unsigned int)f2bf(acc[7]) << 16);
            *(uint4*)&O_lds[n][q * 32 + g * 8] = pk;
        }
    }
    __syncthreads();

    // proj GEMM: out[o][n] = sum_c proj_w[o][c] * O[n][c] + proj_b + x
    short8 bfrag[4][4];
#pragma unroll
    for (int nt = 0; nt < 4; ++nt)
#pragma unroll
        for (int ks = 0; ks < 4; ++ks)
            bfrag[nt][ks] = *(const short8*)&O_lds[nt * 16 + l15][ks * 32 + q4 * 8];

#pragma unroll
    for (int ot = 0; ot < 2; ++ot) {
        int o0 = wave * 32 + ot * 16;
        short8 af[4];
#pragma unroll
        for (int ks = 0; ks < 4; ++ks)
            af[ks] = ldg8(wp + (size_t)(o0 + l15) * 128 + ks * 32 + q4 * 8);
        float pb[4];
#pragma unroll
        for (int r = 0; r < 4; ++r) pb[r] = proj_b[o0 + q4 * 4 + r];

#pragma unroll
        for (int nt = 0; nt < 4; ++nt) {
            f32x4 acc = {0.f, 0.f, 0.f, 0.f};
#pragma unroll
            for (int ks = 0; ks < 4; ++ks)
                acc = MFMA_BF16(af[ks], bfrag[nt][ks], acc);
#pragma unroll
            for (int r = 0; r < 4; ++r) {
                size_t idx = ((size_t)(b * 128 + o0 + q4 * 4 + r) << 12) + i0 + nt * 16 + l15;
                out[idx] = x[idx] + acc[r] + pb[r];
            }
        }
    }
}

// ---------------- launch ----------------
extern "C" void kernel_launch(void* const* d_in, const int* in_sizes, int n_in,
                              void* d_out, int out_size, void* d_ws, size_t ws_size,
                              hipStream_t stream) {
    const float* x      = (const float*)d_in[0];
    const float* gn_w   = (const float*)d_in[1];
    const float* gn_b   = (const float*)d_in[2];
    const float* qkv_w  = (const float*)d_in[3];
    const float* qkv_b  = (const float*)d_in[4];
    const float* proj_w = (const float*)d_in[5];
    const float* proj_b = (const float*)d_in[6];
    float* out = (float*)d_out;

    char* ws = (char*)d_ws;
    float* sums           = (float*)ws;                              // 512 B (zeroed below)
    unsigned short* wq    = (unsigned short*)(ws + 4096);            // 96 KB
    unsigned short* wp    = (unsigned short*)(ws + 4096 + 98304);    // 32 KB
    unsigned short* q_ws  = (unsigned short*)(ws + ((size_t)1  << 20));  // 8 MB
    unsigned short* k_ws  = (unsigned short*)(ws + ((size_t)9  << 20));  // 8 MB
    unsigned short* v_ws  = (unsigned short*)(ws + ((size_t)17 << 20));  // 8 MB
    unsigned short* o_part= (unsigned short*)(ws + ((size_t)25 << 20));  // 32 MB
    float* ml             = (float*)(ws + ((size_t)57 << 20));           // 512 KB

    hipMemsetAsync(sums, 0, 512, stream);
    k_pre<<<1088, 256, 0, stream>>>(x, sums, qkv_w, proj_w, wq, wp);
    k_qkv<<<512, 256, 0, stream>>>(x, sums, gn_w, gn_b, wq, qkv_b, q_ws, k_ws, v_ws);
    k_attn_part<<<2048, 256, 0, stream>>>(q_ws, k_ws, v_ws, o_part, ml);
    k_merge_proj<<<512, 256, 0, stream>>>(o_part, ml, x, wp, proj_b, out);
}

// Round 9
// 218.391 us; speedup vs baseline: 1.2827x; 1.2827x over previous
//
#include <hip/hip_runtime.h>
#include <stdint.h>

// B=8, C=128, N=4096 (64x64), GROUPS=8 (16 ch/group)
// Split-KV flash attention, 32x32x16 MFMA quadrants, max-free base-2 softmax.
// R9: K back in LDS (global-MFMA streaming regressed twice: r3=V, r8=K).
//     S^T operand order (MFMA(kf,qf)) -> j lands in reg space -> packed b64 P writes.
//     k_qkv V tiles computed transposed -> direct packed global stores, no v_stage.

typedef __attribute__((ext_vector_type(8))) short short8;
typedef __attribute__((ext_vector_type(4))) float f32x4;
typedef __attribute__((ext_vector_type(16))) float f32x16;

#define MFMA_BF16(a, b, c) __builtin_amdgcn_mfma_f32_16x16x32_bf16((a), (b), (c), 0, 0, 0)
#define MFMA32(a, b, c) __builtin_amdgcn_mfma_f32_32x32x16_bf16((a), (b), (c), 0, 0, 0)
#define EXP2(x) __builtin_amdgcn_exp2f(x)

// (1/sqrt(128)) * log2(e) — folded into Q at k_qkv store time (softmax runs in base 2)
#define QSCALE 0.12751743f

__device__ __forceinline__ unsigned short f2bf(float f) {
    unsigned int u = __builtin_bit_cast(unsigned int, f);
    u += 0x7FFFu + ((u >> 16) & 1u);   // RNE (finite values only)
    return (unsigned short)(u >> 16);
}
__device__ __forceinline__ float bf2f(unsigned int lo16) {
    return __builtin_bit_cast(float, lo16 << 16);
}
__device__ __forceinline__ short8 ldg8(const unsigned short* p) {
    return __builtin_bit_cast(short8, *(const uint4*)p);
}

// ---------------- Kernel 1: GroupNorm partial sums (atomic) + weight bf16 conv ------
__global__ __launch_bounds__(256) void k_pre(const float* __restrict__ x,
                                             float* __restrict__ sums,
                                             const float* __restrict__ qkv_w,
                                             const float* __restrict__ proj_w,
                                             unsigned short* __restrict__ wq,
                                             unsigned short* __restrict__ wp) {
    if (blockIdx.x >= 1024) {            // weight conversion: 64 blocks x 1024 elems
        int i = ((blockIdx.x - 1024) * 256 + threadIdx.x) * 4;
        const float* src; unsigned short* dst; int off;
        if (i < 49152) { src = qkv_w; dst = wq; off = i; }
        else           { src = proj_w; dst = wp; off = i - 49152; }
        float4 v = *(const float4*)(src + off);
        uint2 pk;
        pk.x = (unsigned int)f2bf(v.x) | ((unsigned int)f2bf(v.y) << 16);
        pk.y = (unsigned int)f2bf(v.z) | ((unsigned int)f2bf(v.w) << 16);
        *(uint2*)(dst + off) = pk;
        return;
    }
    int g     = blockIdx.x >> 4;         // 0..63 (b*8+gr); group slab contiguous
    int slice = blockIdx.x & 15;
    const float* p = x + (size_t)g * 65536 + slice * 4096;
    float s = 0.f, sq = 0.f;
#pragma unroll
    for (int i = 0; i < 4; ++i) {
        float4 v = *(const float4*)(p + threadIdx.x * 4 + i * 1024);
        s  += v.x + v.y + v.z + v.w;
        sq += v.x*v.x + v.y*v.y + v.z*v.z + v.w*v.w;
    }
#pragma unroll
    for (int m = 1; m < 64; m <<= 1) { s += __shfl_xor(s, m, 64); sq += __shfl_xor(sq, m, 64); }
    __shared__ float ss[4], ssq[4];
    int w = threadIdx.x >> 6;
    if ((threadIdx.x & 63) == 0) { ss[w] = s; ssq[w] = sq; }
    __syncthreads();
    if (threadIdx.x == 0) {
        atomicAdd(&sums[g * 2],     ss[0] + ss[1] + ss[2] + ss[3]);
        atomicAdd(&sums[g * 2 + 1], ssq[0] + ssq[1] + ssq[2] + ssq[3]);
    }
}

// ---------------- Kernel 2: fused GroupNorm-apply + QKV GEMM ----------------
// Q (pre-scaled by QSCALE), K as bf16 [b][n][c]; V as bf16 [b][c][n].
// V tiles computed transposed (MFMA(bfrag, af) -> D[n][c]) -> packed 8B global stores.
__global__ __launch_bounds__(256) void k_qkv(const float* __restrict__ x,
                                             const float* __restrict__ sums,
                                             const float* __restrict__ gn_w,
                                             const float* __restrict__ gn_b,
                                             const unsigned short* __restrict__ wq,
                                             const float* __restrict__ qkv_b,
                                             unsigned short* __restrict__ q_ws,
                                             unsigned short* __restrict__ k_ws,
                                             unsigned short* __restrict__ v_ws) {
    __shared__ unsigned short h_lds[64][136];   // [n][c], +8 pad
    const int tid  = threadIdx.x;
    const int b    = blockIdx.x >> 6;
    const int n0   = (blockIdx.x & 63) << 6;
    const int lane = tid & 63, wave = tid >> 6;
    const int l15  = lane & 15, q4 = lane >> 4;

    // normalize x tile -> bf16 -> h_lds[n][c]
    {
        int cb = tid >> 4;            // 0..15
        int nn = (tid & 15) << 2;     // 0..60
#pragma unroll
        for (int k = 0; k < 8; ++k) {
            int c = cb + (k << 4);
            float4 v = *(const float4*)(x + ((size_t)(b * 128 + c) << 12) + n0 + nn);
            int g = c >> 4;
            float ts = sums[(b * 8 + g) * 2];
            float tq = sums[(b * 8 + g) * 2 + 1];
            float mean = ts * (1.f / 65536.f);
            float var  = tq * (1.f / 65536.f) - mean * mean;
            float rstd = rsqrtf(var + 1e-5f);
            float ga = gn_w[c] * rstd;
            float be = gn_b[c] - mean * ga;
            h_lds[nn + 0][c] = f2bf(v.x * ga + be);
            h_lds[nn + 1][c] = f2bf(v.y * ga + be);
            h_lds[nn + 2][c] = f2bf(v.z * ga + be);
            h_lds[nn + 3][c] = f2bf(v.w * ga + be);
        }
    }
    __syncthreads();

    short8 bfrag[4][4];               // h[n][c]: as B (k=c, n=l15) or as A (m=n, k=c)
#pragma unroll
    for (int nt = 0; nt < 4; ++nt)
#pragma unroll
        for (int ks = 0; ks < 4; ++ks)
            bfrag[nt][ks] = *(const short8*)&h_lds[nt * 16 + l15][ks * 32 + q4 * 8];

#pragma unroll
    for (int ot = 0; ot < 6; ++ot) {
        int o0 = wave * 96 + ot * 16;                 // 16-row tile is purely Q, K, or V
        short8 af[4];                                 // w[o][c]: as A (m=o) or as B (n=o)
#pragma unroll
        for (int ks = 0; ks < 4; ++ks)
            af[ks] = ldg8(wq + (size_t)(o0 + l15) * 128 + ks * 32 + q4 * 8);

        if (o0 < 256) {               // Q or K: D[row=o(reg)][col=n=l15] -> [n][c] layout
            float bias[4];
#pragma unroll
            for (int r = 0; r < 4; ++r) bias[r] = qkv_b[o0 + q4 * 4 + r];
            float qs = (o0 < 128) ? QSCALE : 1.0f;
#pragma unroll
            for (int nt = 0; nt < 4; ++nt) {
                f32x4 acc = {0.f, 0.f, 0.f, 0.f};
#pragma unroll
                for (int ks = 0; ks < 4; ++ks)
                    acc = MFMA_BF16(af[ks], bfrag[nt][ks], acc);
                int n = n0 + nt * 16 + l15;
                unsigned short* dst = (o0 < 128) ? q_ws : k_ws;
                int oo = (o0 < 128) ? o0 : (o0 - 128);
                unsigned int lo = (unsigned int)f2bf((acc[0] + bias[0]) * qs) |
                                  ((unsigned int)f2bf((acc[1] + bias[1]) * qs) << 16);
                unsigned int hi = (unsigned int)f2bf((acc[2] + bias[2]) * qs) |
                                  ((unsigned int)f2bf((acc[3] + bias[3]) * qs) << 16);
                uint2 pk; pk.x = lo; pk.y = hi;
                *(uint2*)&dst[((size_t)(b * 4096 + n) << 7) + oo + q4 * 4] = pk;
            }
        } else {                      // V transposed: D[row=n(reg)][col=c=l15] -> [c][n]
            int c = o0 - 256 + l15;
            float vb = qkv_b[o0 + l15];
            unsigned short* vrow = v_ws + ((size_t)(b * 128 + c) << 12) + n0;
#pragma unroll
            for (int nt = 0; nt < 4; ++nt) {
                f32x4 acc = {0.f, 0.f, 0.f, 0.f};
#pragma unroll
                for (int ks = 0; ks < 4; ++ks)
                    acc = MFMA_BF16(bfrag[nt][ks], af[ks], acc);
                // n = nt*16 + q4*4 + r (4 consecutive) at fixed c -> packed 8B store
                unsigned int lo = (unsigned int)f2bf(acc[0] + vb) |
                                  ((unsigned int)f2bf(acc[1] + vb) << 16);
                unsigned int hi = (unsigned int)f2bf(acc[2] + vb) |
                                  ((unsigned int)f2bf(acc[3] + vb) << 16);
                uint2 pk; pk.x = lo; pk.y = hi;
                *(uint2*)&vrow[nt * 16 + q4 * 4] = pk;
            }
        }
    }
}

// ---------------- Kernel 3: flash attention partial (split-KV, 32x32 quadrants) ----
// block = 256 threads / 4 waves = (b, i-tile, chunk); chunk covers 1024 j.
// QK computes S^T: MFMA(A=kf, B=qf) -> D[j(reg)][i(lane)], so P writes are 4 packed
// b64 per wave-quadrant into P_lds[i][j]. PV reads (A=P[i][j], B=V^T) unchanged.
// All MFMA operands from LDS (global-streaming regressed in r3/r8); nothing
// register-held across MFMA regions (r5/r6 spill lesson).
__global__ __launch_bounds__(256, 3) void k_attn_part(const unsigned short* __restrict__ q_ws,
                                                      const unsigned short* __restrict__ k_ws,
                                                      const unsigned short* __restrict__ v_ws,
                                                      unsigned short* __restrict__ o_part,
                                                      float* __restrict__ ml) {
    __shared__ unsigned short K_lds[64][136];   // [j][c], +8 pad   (17408 B)
    __shared__ unsigned short V_lds[128][72];   // [c][j], +8 pad   (18432 B)
    __shared__ unsigned short P_lds[64][72];    // [i][j], +8 pad   ( 9216 B)  ~45 KB

    const int tid   = threadIdx.x;
    const int chunk = blockIdx.x & 3;
    const int tile  = (blockIdx.x >> 2) & 63;
    const int b     = blockIdx.x >> 8;
    const int i0    = tile << 6;
    const int lane  = tid & 63, wave = tid >> 6;
    const int ih    = wave >> 1, jh = wave & 1;   // jh doubles as c-half in PV
    const int l31   = lane & 31, h = lane >> 5;

    const short8 ones = {(short)0x3F80, (short)0x3F80, (short)0x3F80, (short)0x3F80,
                         (short)0x3F80, (short)0x3F80, (short)0x3F80, (short)0x3F80};

    // Q frags (pre-scaled by QSCALE): lane holds i=l31, k=c=ks*16+h*8+e
    // (identical lane-mapping whether used as A or as B operand)
    short8 qf[8];
    {
        const unsigned short* qp =
            q_ws + ((size_t)(b * 4096 + i0 + ih * 32 + l31) << 7) + h * 8;
#pragma unroll
        for (int ks = 0; ks < 8; ++ks) qf[ks] = ldg8(qp + ks * 16);
    }

    f32x16 acc[2];                           // O[i(reg)][c = jh*64 + ct*32 + l31]
    f32x16 lacc;                             // row sums (every col identical)
#pragma unroll
    for (int e = 0; e < 16; ++e) { lacc[e] = 0.f; acc[0][e] = 0.f; acc[1][e] = 0.f; }

    const unsigned short* kbase = k_ws + ((size_t)b << 19);
    const unsigned short* vsrc  = v_ws + ((size_t)b << 19) +
                                  ((size_t)(tid >> 1) << 12) + (tid & 1) * 32;

    for (int it = 0; it < 16; ++it) {
        int j0 = (chunk << 10) + (it << 6);
        __syncthreads();                      // prev iter's K/V/P reads done
        {   // stage K tile: 16 KB contiguous slab -> [j][136-pitch]
            const unsigned short* ksrc = kbase + ((size_t)j0 << 7);
#pragma unroll
            for (int i = 0; i < 4; ++i) {
                int f = i * 256 + tid;        // 0..1023 16B-chunks
                int row = f >> 4, q = (f & 15) << 3;
                *(uint4*)&K_lds[row][q] = *(const uint4*)(ksrc + f * 8);
            }
            // stage V tile [128 c][72-pitch j] — straight to LDS, no reg hold
            const unsigned short* vp = vsrc + j0;
            uint4* vd = (uint4*)&V_lds[tid >> 1][(tid & 1) * 32];
#pragma unroll
            for (int k = 0; k < 4; ++k) vd[k] = *(const uint4*)(vp + k * 8);
        }
        __syncthreads();                      // K, V visible

        // S^T quadrant = K Q^T : D row = j = (r&3)+8(r>>2)+4h (in jh half),
        //                        col = i = l31 (in ih half)
        f32x16 s;
#pragma unroll
        for (int e = 0; e < 16; ++e) s[e] = 0.f;
#pragma unroll
        for (int ks = 0; ks < 8; ++ks) {
            short8 kf = *(const short8*)&K_lds[jh * 32 + l31][ks * 16 + h * 8];
            s = MFMA32(kf, qf[ks], s);
        }

        // max-free softmax: p = exp2(min(s,30)); packed b64 writes into P_lds[i][j]
        // (reg-quad rr holds 4 consecutive j = jh*32 + rr*8 + 4h + {0..3})
        unsigned short* prow = &P_lds[ih * 32 + l31][jh * 32 + (h << 2)];
#pragma unroll
        for (int rr = 0; rr < 4; ++rr) {
            unsigned int lo = (unsigned int)f2bf(EXP2(fminf(s[rr * 4 + 0], 30.f))) |
                              ((unsigned int)f2bf(EXP2(fminf(s[rr * 4 + 1], 30.f))) << 16);
            unsigned int hi = (unsigned int)f2bf(EXP2(fminf(s[rr * 4 + 2], 30.f))) |
                              ((unsigned int)f2bf(EXP2(fminf(s[rr * 4 + 3], 30.f))) << 16);
            uint2 pk; pk.x = lo; pk.y = hi;
            *(uint2*)(prow + rr * 8) = pk;
        }
        __syncthreads();                      // V + P visible

        // O += P V^T ; l += P.1   (A = P[i][j], B = V^T[j][c])
#pragma unroll
        for (int ks = 0; ks < 4; ++ks) {
            short8 pf = *(const short8*)&P_lds[ih * 32 + l31][ks * 16 + h * 8];
            lacc = MFMA32(pf, ones, lacc);
#pragma unroll
            for (int ct = 0; ct < 2; ++ct) {
                short8 vf = *(const short8*)&V_lds[jh * 64 + ct * 32 + l31][ks * 16 + h * 8];
                acc[ct] = MFMA32(pf, vf, acc[ct]);
            }
        }
    }

    // epilogue: normalize rows, store bf16 partial [n][c] + m' = log2(l)
    size_t pbase = (size_t)((b * 64 + tile) * 4 + chunk) * 8192;
    float rl[16];
#pragma unroll
    for (int r = 0; r < 16; ++r) rl[r] = 1.0f / lacc[r];
#pragma unroll
    for (int ct = 0; ct < 2; ++ct)
#pragma unroll
        for (int r = 0; r < 16; ++r) {
            int row = ih * 32 + (r & 3) + ((r >> 2) << 3) + (h << 2);
            o_part[pbase + (size_t)row * 128 + jh * 64 + ct * 32 + l31] =
                f2bf(acc[ct][r] * rl[r]);
        }
    if (l31 == 0 && jh == 0) {
        int mb = ((b * 64 + tile) * 4 + chunk) * 64;
#pragma unroll
        for (int r = 0; r < 16; ++r)
            ml[mb + ih * 32 + (r & 3) + ((r >> 2) << 3) + (h << 2)] = __log2f(lacc[r]);
    }
}

// ---------------- Kernel 4: merge partials + proj GEMM + bias + residual ----------
__global__ __launch_bounds__(256) void k_merge_proj(const unsigned short* __restrict__ o_part,
                                                    const float* __restrict__ ml,
                                                    const float* __restrict__ x,
                                                    const unsigned short* __restrict__ wp,
                                                    const float* __restrict__ proj_b,
                                                    float* __restrict__ out) {
    __shared__ unsigned short O_lds[64][136];
    __shared__ float wgt[64][4];
    const int tid  = threadIdx.x;
    const int b    = blockIdx.x >> 6;
    const int tile = blockIdx.x & 63;
    const int i0   = tile << 6;
    const int lane = tid & 63, wave = tid >> 6;
    const int l15  = lane & 15, q4 = lane >> 4;
    const int tb   = (b * 64 + tile) * 4;

    if (tid < 64) {
        float m0 = ml[(tb + 0) * 64 + tid], m1 = ml[(tb + 1) * 64 + tid];
        float m2 = ml[(tb + 2) * 64 + tid], m3 = ml[(tb + 3) * 64 + tid];
        float M = fmaxf(fmaxf(m0, m1), fmaxf(m2, m3));
        float w0 = EXP2(m0 - M), w1 = EXP2(m1 - M), w2 = EXP2(m2 - M), w3 = EXP2(m3 - M);
        float rW = 1.0f / (w0 + w1 + w2 + w3);
        wgt[tid][0] = w0 * rW; wgt[tid][1] = w1 * rW;
        wgt[tid][2] = w2 * rW; wgt[tid][3] = w3 * rW;
    }
    __syncthreads();

    {   // weighted merge: thread t -> row n=t>>2, 32-c quarter q=t&3
        int n = tid >> 2, q = tid & 3;
        float w[4];
#pragma unroll
        for (int ch = 0; ch < 4; ++ch) w[ch] = wgt[n][ch];
#pragma unroll
        for (int g = 0; g < 4; ++g) {             // 8 c per group
            float acc[8];
#pragma unroll
            for (int e = 0; e < 8; ++e) acc[e] = 0.f;
#pragma unroll
            for (int ch = 0; ch < 4; ++ch) {
                const unsigned short* p =
                    o_part + (size_t)(tb + ch) * 8192 + (size_t)n * 128 + q * 32 + g * 8;
                uint4 v = *(const uint4*)p;
                float wc = w[ch];
                acc[0] += wc * bf2f(v.x & 0xFFFF); acc[1] += wc * bf2f(v.x >> 16);
                acc[2] += wc * bf2f(v.y & 0xFFFF); acc[3] += wc * bf2f(v.y >> 16);
                acc[4] += wc * bf2f(v.z & 0xFFFF); acc[5] += wc * bf2f(v.z >> 16);
                acc[6] += wc * bf2f(v.w & 0xFFFF); acc[7] += wc * bf2f(v.w >> 16);
            }
            uint4 pk;
            pk.x = (unsigned int)f2bf(acc[0]) | ((unsigned int)f2bf(acc[1]) << 16);
            pk.y = (unsigned int)f2bf(acc[2]) | ((unsigned int)f2bf(acc[3]) << 16);
            pk.z = (unsigned int)f2bf(acc[4]) | ((unsigned int)f2bf(acc[5]) << 16);
            pk.w = (unsigned int)f2bf(acc[6]) | ((unsigned int)f2bf(acc[7]) << 16);
            *(uint4*)&O_lds[n][q * 32 + g * 8] = pk;
        }
    }
    __syncthreads();

    // proj GEMM: out[o][n] = sum_c proj_w[o][c] * O[n][c] + proj_b + x
    short8 bfrag[4][4];
#pragma unroll
    for (int nt = 0; nt < 4; ++nt)
#pragma unroll
        for (int ks = 0; ks < 4; ++ks)
            bfrag[nt][ks] = *(const short8*)&O_lds[nt * 16 + l15][ks * 32 + q4 * 8];

#pragma unroll
    for (int ot = 0; ot < 2; ++ot) {
        int o0 = wave * 32 + ot * 16;
        short8 af[4];
#pragma unroll
        for (int ks = 0; ks < 4; ++ks)
            af[ks] = ldg8(wp + (size_t)(o0 + l15) * 128 + ks * 32 + q4 * 8);
        float pb[4];
#pragma unroll
        for (int r = 0; r < 4; ++r) pb[r] = proj_b[o0 + q4 * 4 + r];

#pragma unroll
        for (int nt = 0; nt < 4; ++nt) {
            f32x4 acc = {0.f, 0.f, 0.f, 0.f};
#pragma unroll
            for (int ks = 0; ks < 4; ++ks)
                acc = MFMA_BF16(af[ks], bfrag[nt][ks], acc);
#pragma unroll
            for (int r = 0; r < 4; ++r) {
                size_t idx = ((size_t)(b * 128 + o0 + q4 * 4 + r) << 12) + i0 + nt * 16 + l15;
                out[idx] = x[idx] + acc[r] + pb[r];
            }
        }
    }
}

// ---------------- launch ----------------
extern "C" void kernel_launch(void* const* d_in, const int* in_sizes, int n_in,
                              void* d_out, int out_size, void* d_ws, size_t ws_size,
                              hipStream_t stream) {
    const float* x      = (const float*)d_in[0];
    const float* gn_w   = (const float*)d_in[1];
    const float* gn_b   = (const float*)d_in[2];
    const float* qkv_w  = (const float*)d_in[3];
    const float* qkv_b  = (const float*)d_in[4];
    const float* proj_w = (const float*)d_in[5];
    const float* proj_b = (const float*)d_in[6];
    float* out = (float*)d_out;

    char* ws = (char*)d_ws;
    float* sums           = (float*)ws;                              // 512 B (zeroed below)
    unsigned short* wq    = (unsigned short*)(ws + 4096);            // 96 KB
    unsigned short* wp    = (unsigned short*)(ws + 4096 + 98304);    // 32 KB
    unsigned short* q_ws  = (unsigned short*)(ws + ((size_t)1  << 20));  // 8 MB
    unsigned short* k_ws  = (unsigned short*)(ws + ((size_t)9  << 20));  // 8 MB
    unsigned short* v_ws  = (unsigned short*)(ws + ((size_t)17 << 20));  // 8 MB
    unsigned short* o_part= (unsigned short*)(ws + ((size_t)25 << 20));  // 32 MB
    float* ml             = (float*)(ws + ((size_t)57 << 20));           // 512 KB

    hipMemsetAsync(sums, 0, 512, stream);
    k_pre<<<1088, 256, 0, stream>>>(x, sums, qkv_w, proj_w, wq, wp);
    k_qkv<<<512, 256, 0, stream>>>(x, sums, gn_w, gn_b, wq, qkv_b, q_ws, k_ws, v_ws);
    k_attn_part<<<2048, 256, 0, stream>>>(q_ws, k_ws, v_ws, o_part, ml);
    k_merge_proj<<<512, 256, 0, stream>>>(o_part, ml, x, wp, proj_b, out);
}